// Round 7
// baseline (152.635 us; speedup 1.0000x reference)
//
#include <hip/hip_runtime.h>

// CIN forward: B=2048, F=32, DIM=64, layers (128,128)
// out[b, 0:64]   = sum_d relu(W0 @ z0 + b0)[64:128, d]
// out[b, 64:192] = sum_d relu(W1 @ z1 + b1)[0:128, d]
// z0[h*32+m, d] = x[h,d]*x[m,d]   (h,m in [0,32))
// z1[h*32+m, d] = h1[h,d]*x[m,d]  (h in [0,64), m in [0,32)), h1 = layer0 rows 0..63
//
// R7: R5c shell (free-running, 256 thr, 2 batches/block — R6 proved per-iter
// barriers cost more than duplicate-W L2 traffic), minus its overhead:
//   - manual 2x-unrolled ping-pong register sets (A/B by compile-time parity)
//     kills ~18 rotation movs + clamp math per K-step (~45% of non-MFMA insts)
//   - s_setprio(1) around each 16-MFMA cluster: identical waves phase-lock
//     (VALU phases align, MFMA pipe idles at 56%); priority staggers them (T5)
//   - launch_bounds(256,3): achieved occupancy was ~2.8 waves/SIMD; relax the
//     128-reg cap so the scheduler isn't forced to remat
//   - L0 tail pair prefetches L1 tile 0 into regs across the epilogue
//
// A-frag swizzle (16x16x32): wsw[ks*4096 + s*512 + lane*8 + j]
//   = W[(s*16 + (lane&15))*K + ks*32 + (lane>>4)*8 + j]

#define BATCH 2048
#define FSZ   32
#define DIM   64
#define K0    1024
#define K1    2048
#define OUTC  192

#define W0_ELEMS (128 * K0)            // 131072 f16
#define W1_ELEMS (128 * K1)            // 262144 f16
#define TOT_ELEMS (W0_ELEMS + W1_ELEMS)
#define CVT_THREADS (TOT_ELEMS / 4)    // 98304 -> 384 blocks

typedef _Float16 v8h __attribute__((ext_vector_type(8)));
typedef _Float16 v4h __attribute__((ext_vector_type(4)));
typedef float    v4f __attribute__((ext_vector_type(4)));

#define XT_PITCH 40   // xT[d][m]: 80B rows, 16B-aligned v8h loads

// One thread per 4 output f16: coalesced 8B stores, aligned float4 reads.
__global__ void convert_w_kernel(const float* __restrict__ W0,
                                 const float* __restrict__ W1,
                                 _Float16* __restrict__ wsw) {
    int t = blockIdx.x * blockDim.x + threadIdx.x;
    if (t >= CVT_THREADS) return;
    int e = t * 4;
    const float* src;
    _Float16* dst;
    if (e < W0_ELEMS) {
        int j0 = e & 7, lane = (e >> 3) & 63, s = (e >> 9) & 7, ks = e >> 12;
        src = W0 + (size_t)(s * 16 + (lane & 15)) * K0
                 + ks * 32 + (lane >> 4) * 8 + j0;
        dst = wsw + e;
    } else {
        int u = e - W0_ELEMS;
        int j0 = u & 7, lane = (u >> 3) & 63, s = (u >> 9) & 7, ks = u >> 12;
        src = W1 + (size_t)(s * 16 + (lane & 15)) * K1
                 + ks * 32 + (lane >> 4) * 8 + j0;
        dst = wsw + W0_ELEMS + u;
    }
    float4 v = *(const float4*)src;
    dst[0] = (_Float16)v.x;
    dst[1] = (_Float16)v.y;
    dst[2] = (_Float16)v.z;
    dst[3] = (_Float16)v.w;
}

__device__ __forceinline__ void loadW4(v8h a[4], const _Float16* p) {
    #pragma unroll
    for (int i = 0; i < 4; ++i) a[i] = *(const v8h*)(p + i * 512);
}

__device__ __forceinline__ v4f mfma16(v8h a, v8h b, v4f c) {
    return __builtin_amdgcn_mfma_f32_16x16x32_f16(a, b, c, 0, 0, 0);
}

// One K-step: 4 B-fragments (broadcast-mul) feeding 16 MFMAs, setprio-wrapped.
__device__ __forceinline__ void compute16(const v8h a[4], v4h sv,
                                          const v8h xv8[4], v4f acc[4][4]) {
    __builtin_amdgcn_s_setprio(1);
    #pragma unroll
    for (int t = 0; t < 4; ++t) {
        _Float16 s = sv[t];
        v8h s8 = {s, s, s, s, s, s, s, s};
        v8h bfr = s8 * xv8[t];
        acc[0][t] = mfma16(a[0], bfr, acc[0][t]);
        acc[1][t] = mfma16(a[1], bfr, acc[1][t]);
        acc[2][t] = mfma16(a[2], bfr, acc[2][t]);
        acc[3][t] = mfma16(a[3], bfr, acc[3][t]);
    }
    __builtin_amdgcn_s_setprio(0);
}

__global__ __launch_bounds__(256, 3) void cin_kernel(
    const float* __restrict__ X,      // (B, 32, 64) fp32
    const float* __restrict__ b0,     // (128,)
    const float* __restrict__ b1,     // (128,)
    const _Float16* __restrict__ Wsw, // swizzled W0 then W1 (f16)
    float* __restrict__ out)          // (B, 192) fp32
{
    __shared__ _Float16 xT[2][DIM * XT_PITCH];   // xT[p][d][m]      (10240 B)
    __shared__ _Float16 xS[2][FSZ * 64];         // xS[p][m][c*4+t]  ( 8192 B)
    __shared__ _Float16 h1S[2][64 * 64];         // h1S[p][h][c*4+t] (16384 B)

    const int b0i  = blockIdx.x * 2;
    const int tid  = threadIdx.x;
    const int wave = tid >> 6;
    const int lane = tid & 63;
    const int p    = wave & 1;        // batch member
    const int rh   = wave >> 1;       // row half (64 rows)
    const int quad = lane >> 4;
    const int col  = lane & 15;

    // ---- stage both batches' x -> LDS (both layouts, f16) ----
    #pragma unroll
    for (int i = 0; i < 4; ++i) {
        int idx = tid + i * 256;               // float4 index 0..1023
        int pp = idx >> 9, r4 = idx & 511;
        float4 v = *(const float4*)(X + (size_t)(b0i + pp) * (FSZ * DIM) + r4 * 4);
        int m = (r4 * 4) >> 6, d = (r4 * 4) & 63;
        int tq = d >> 4, cc = d & 15;          // constant within the float4
        _Float16 f0 = (_Float16)v.x, f1 = (_Float16)v.y,
                 f2 = (_Float16)v.z, f3 = (_Float16)v.w;
        xT[pp][(d + 0) * XT_PITCH + m] = f0;
        xT[pp][(d + 1) * XT_PITCH + m] = f1;
        xT[pp][(d + 2) * XT_PITCH + m] = f2;
        xT[pp][(d + 3) * XT_PITCH + m] = f3;
        xS[pp][m * 64 + (cc + 0) * 4 + tq] = f0;
        xS[pp][m * 64 + (cc + 1) * 4 + tq] = f1;
        xS[pp][m * 64 + (cc + 2) * 4 + tq] = f2;
        xS[pp][m * 64 + (cc + 3) * 4 + tq] = f3;
    }
    __syncthreads();

    // K-invariant x parts of B fragments: xv8[t][j] = x[quad*8+j][16t+col]
    v8h xv8[4];
    #pragma unroll
    for (int t = 0; t < 4; ++t)
        xv8[t] = *(const v8h*)(&xT[p][(16 * t + col) * XT_PITCH + quad * 8]);

    const _Float16* WbL0 = Wsw + (size_t)rh * 2048 + (size_t)lane * 8;
    const _Float16* WbL1 = WbL0 + W0_ELEMS;
    const _Float16* xSp  = &xS[p][col * 4];
    const _Float16* h1Sp = &h1S[p][col * 4];

    // ================= layer 0 (32 K-steps, 2x ping-pong) =================
    v4f acc[4][4];
    #pragma unroll
    for (int f = 0; f < 4; ++f)
        #pragma unroll
        for (int t = 0; t < 4; ++t) acc[f][t] = (v4f)0.0f;

    v8h A[4], B[4];
    v4h svA, svB;
    loadW4(A, WbL0);
    svA = *(const v4h*)(xSp);
    #pragma unroll 1
    for (int kp = 0; kp < 15; ++kp) {          // ks = 2kp, 2kp+1
        const _Float16* Wc = WbL0 + (size_t)kp * 8192;
        loadW4(B, Wc + 4096);
        svB = *(const v4h*)(xSp + (2 * kp + 1) * 64);
        compute16(A, svA, xv8, acc);           // tile 2kp
        loadW4(A, Wc + 8192);
        svA = *(const v4h*)(xSp + (2 * kp + 2) * 64);
        compute16(B, svB, xv8, acc);           // tile 2kp+1
    }
    // tail: ks=30,31; second prefetch pulls layer-1 tile 0 across the epilogue
    loadW4(B, WbL0 + (size_t)31 * 4096);
    svB = *(const v4h*)(xSp + 31 * 64);
    compute16(A, svA, xv8, acc);               // tile 30
    loadW4(A, WbL1);                           // layer-1 tile 0
    compute16(B, svB, xv8, acc);               // tile 31

    // ---- epilogue 0 ----
    // rh=0: rows 0..63 -> h1S[p] (packed v4h writes); rh=1: rows 64..127 -> out
    if (rh == 0) {
        #pragma unroll
        for (int f = 0; f < 4; ++f) {
            #pragma unroll
            for (int reg = 0; reg < 4; ++reg) {
                const int o = f * 16 + quad * 4 + reg;
                const float bias = b0[o];
                v4h pk;
                #pragma unroll
                for (int t = 0; t < 4; ++t) {
                    float v = acc[f][t][reg] + bias;
                    v = v > 0.0f ? v : 0.0f;
                    pk[t] = (_Float16)v;
                }
                *(v4h*)(&h1S[p][o * 64 + col * 4]) = pk;
            }
        }
    } else {
        #pragma unroll
        for (int f = 0; f < 4; ++f) {
            #pragma unroll
            for (int reg = 0; reg < 4; ++reg) {
                const int o = 64 + f * 16 + quad * 4 + reg;
                const float bias = b0[o];
                float s = 0.0f;
                #pragma unroll
                for (int t = 0; t < 4; ++t) {
                    float v = acc[f][t][reg] + bias;
                    s += (v > 0.0f ? v : 0.0f);
                }
                s += __shfl_xor(s, 1);
                s += __shfl_xor(s, 2);
                s += __shfl_xor(s, 4);
                s += __shfl_xor(s, 8);
                if (col == 0) out[(size_t)(b0i + p) * OUTC + (o - 64)] = s;
            }
        }
    }
    __syncthreads();   // h1S visible to all waves

    // ================= layer 1 (64 K-steps, 2x ping-pong) =================
    #pragma unroll
    for (int f = 0; f < 4; ++f)
        #pragma unroll
        for (int t = 0; t < 4; ++t) acc[f][t] = (v4f)0.0f;

    // A already holds layer-1 tile 0 (prefetched before the epilogue)
    svA = *(const v4h*)(h1Sp);
    #pragma unroll 1
    for (int kp = 0; kp < 31; ++kp) {          // ks = 2kp, 2kp+1
        const _Float16* Wc = WbL1 + (size_t)kp * 8192;
        loadW4(B, Wc + 4096);
        svB = *(const v4h*)(h1Sp + (2 * kp + 1) * 64);
        compute16(A, svA, xv8, acc);           // tile 2kp
        loadW4(A, Wc + 8192);
        svA = *(const v4h*)(h1Sp + (2 * kp + 2) * 64);
        compute16(B, svB, xv8, acc);           // tile 2kp+1
    }
    // tail: ks=62,63 (no further prefetch)
    loadW4(B, WbL1 + (size_t)63 * 4096);
    svB = *(const v4h*)(h1Sp + 63 * 64);
    compute16(A, svA, xv8, acc);               // tile 62
    compute16(B, svB, xv8, acc);               // tile 63

    // ---- epilogue 1: wave's 64 rows -> out[b, 64+o] ----
    #pragma unroll
    for (int f = 0; f < 4; ++f) {
        #pragma unroll
        for (int reg = 0; reg < 4; ++reg) {
            const int o = rh * 64 + f * 16 + quad * 4 + reg;
            const float bias = b1[o];
            float s = 0.0f;
            #pragma unroll
            for (int t = 0; t < 4; ++t) {
                float v = acc[f][t][reg] + bias;
                s += (v > 0.0f ? v : 0.0f);
            }
            s += __shfl_xor(s, 1);
            s += __shfl_xor(s, 2);
            s += __shfl_xor(s, 4);
            s += __shfl_xor(s, 8);
            if (col == 0) out[(size_t)(b0i + p) * OUTC + 64 + o] = s;
        }
    }
}

extern "C" void kernel_launch(void* const* d_in, const int* in_sizes, int n_in,
                              void* d_out, int out_size, void* d_ws, size_t ws_size,
                              hipStream_t stream) {
    const float* X  = (const float*)d_in[0];
    const float* W0 = (const float*)d_in[1];
    const float* b0 = (const float*)d_in[2];
    const float* W1 = (const float*)d_in[3];
    const float* b1 = (const float*)d_in[4];
    float* out = (float*)d_out;
    _Float16* wsw = (_Float16*)d_ws;  // needs 768 KB

    convert_w_kernel<<<(CVT_THREADS + 255) / 256, 256, 0, stream>>>(W0, W1, wsw);
    cin_kernel<<<BATCH / 2, 256, 0, stream>>>(X, b0, b1, wsw, out);
}

// Round 8
// 152.341 us; speedup vs baseline: 1.0019x; 1.0019x over previous
//
#include <hip/hip_runtime.h>

// CIN forward: B=2048, F=32, DIM=64, layers (128,128)
// out[b, 0:64]   = sum_d relu(W0 @ z0 + b0)[64:128, d]
// out[b, 64:192] = sum_d relu(W1 @ z1 + b1)[0:128, d]
// z0[h*32+m, d] = x[h,d]*x[m,d]   (h,m in [0,32))
// z1[h*32+m, d] = h1[h,d]*x[m,d]  (h in [0,64), m in [0,32)), h1 = layer0 rows 0..63
//
// R8: R7's ping-pong, properly budgeted. R7 post-mortem: launch_bounds(256,3)
// let VGPR grow 64->84 (total 148 w/ AGPR) -> residency halved to 2 waves/SIMD
// (occupancy 35->24) and cancelled the ping-pong win. The MFMA-work invariant
// (119K cyc/CU) needs 4 waves/SIMD feeding the pipe. So:
//   - __launch_bounds__(256,4): forces total <=128 regs (R5c proved this
//     liveness fits: same A/B+sv ping-pong footprint, VGPR=64)
//   - no setprio (m190: hurts lockstep GEMM; was an unisolated confound in R7)
//   - keep: 2x-unrolled ping-pong (no rotation movs/clamp math), packed v4h
//     sv reads, L0-tail prefetch of L1 tile 0 across the epilogue.
//
// A-frag swizzle (16x16x32): wsw[ks*4096 + s*512 + lane*8 + j]
//   = W[(s*16 + (lane&15))*K + ks*32 + (lane>>4)*8 + j]

#define BATCH 2048
#define FSZ   32
#define DIM   64
#define K0    1024
#define K1    2048
#define OUTC  192

#define W0_ELEMS (128 * K0)            // 131072 f16
#define W1_ELEMS (128 * K1)            // 262144 f16
#define TOT_ELEMS (W0_ELEMS + W1_ELEMS)
#define CVT_THREADS (TOT_ELEMS / 4)    // 98304 -> 384 blocks

typedef _Float16 v8h __attribute__((ext_vector_type(8)));
typedef _Float16 v4h __attribute__((ext_vector_type(4)));
typedef float    v4f __attribute__((ext_vector_type(4)));

#define XT_PITCH 40   // xT[d][m]: 80B rows, 16B-aligned v8h loads

// One thread per 4 output f16: coalesced 8B stores, aligned float4 reads.
__global__ void convert_w_kernel(const float* __restrict__ W0,
                                 const float* __restrict__ W1,
                                 _Float16* __restrict__ wsw) {
    int t = blockIdx.x * blockDim.x + threadIdx.x;
    if (t >= CVT_THREADS) return;
    int e = t * 4;
    const float* src;
    _Float16* dst;
    if (e < W0_ELEMS) {
        int j0 = e & 7, lane = (e >> 3) & 63, s = (e >> 9) & 7, ks = e >> 12;
        src = W0 + (size_t)(s * 16 + (lane & 15)) * K0
                 + ks * 32 + (lane >> 4) * 8 + j0;
        dst = wsw + e;
    } else {
        int u = e - W0_ELEMS;
        int j0 = u & 7, lane = (u >> 3) & 63, s = (u >> 9) & 7, ks = u >> 12;
        src = W1 + (size_t)(s * 16 + (lane & 15)) * K1
                 + ks * 32 + (lane >> 4) * 8 + j0;
        dst = wsw + W0_ELEMS + u;
    }
    float4 v = *(const float4*)src;
    dst[0] = (_Float16)v.x;
    dst[1] = (_Float16)v.y;
    dst[2] = (_Float16)v.z;
    dst[3] = (_Float16)v.w;
}

__device__ __forceinline__ void loadW4(v8h a[4], const _Float16* p) {
    #pragma unroll
    for (int i = 0; i < 4; ++i) a[i] = *(const v8h*)(p + i * 512);
}

__device__ __forceinline__ v4f mfma16(v8h a, v8h b, v4f c) {
    return __builtin_amdgcn_mfma_f32_16x16x32_f16(a, b, c, 0, 0, 0);
}

// One K-step: 4 B-fragments (broadcast-mul) feeding 16 MFMAs.
__device__ __forceinline__ void compute16(const v8h a[4], v4h sv,
                                          const v8h xv8[4], v4f acc[4][4]) {
    #pragma unroll
    for (int t = 0; t < 4; ++t) {
        _Float16 s = sv[t];
        v8h s8 = {s, s, s, s, s, s, s, s};
        v8h bfr = s8 * xv8[t];
        acc[0][t] = mfma16(a[0], bfr, acc[0][t]);
        acc[1][t] = mfma16(a[1], bfr, acc[1][t]);
        acc[2][t] = mfma16(a[2], bfr, acc[2][t]);
        acc[3][t] = mfma16(a[3], bfr, acc[3][t]);
    }
}

__global__ __launch_bounds__(256, 4) void cin_kernel(
    const float* __restrict__ X,      // (B, 32, 64) fp32
    const float* __restrict__ b0,     // (128,)
    const float* __restrict__ b1,     // (128,)
    const _Float16* __restrict__ Wsw, // swizzled W0 then W1 (f16)
    float* __restrict__ out)          // (B, 192) fp32
{
    __shared__ _Float16 xT[2][DIM * XT_PITCH];   // xT[p][d][m]      (10240 B)
    __shared__ _Float16 xS[2][FSZ * 64];         // xS[p][m][c*4+t]  ( 8192 B)
    __shared__ _Float16 h1S[2][64 * 64];         // h1S[p][h][c*4+t] (16384 B)

    const int b0i  = blockIdx.x * 2;
    const int tid  = threadIdx.x;
    const int wave = tid >> 6;
    const int lane = tid & 63;
    const int p    = wave & 1;        // batch member
    const int rh   = wave >> 1;       // row half (64 rows)
    const int quad = lane >> 4;
    const int col  = lane & 15;

    // ---- stage both batches' x -> LDS (both layouts, f16) ----
    #pragma unroll
    for (int i = 0; i < 4; ++i) {
        int idx = tid + i * 256;               // float4 index 0..1023
        int pp = idx >> 9, r4 = idx & 511;
        float4 v = *(const float4*)(X + (size_t)(b0i + pp) * (FSZ * DIM) + r4 * 4);
        int m = (r4 * 4) >> 6, d = (r4 * 4) & 63;
        int tq = d >> 4, cc = d & 15;          // constant within the float4
        _Float16 f0 = (_Float16)v.x, f1 = (_Float16)v.y,
                 f2 = (_Float16)v.z, f3 = (_Float16)v.w;
        xT[pp][(d + 0) * XT_PITCH + m] = f0;
        xT[pp][(d + 1) * XT_PITCH + m] = f1;
        xT[pp][(d + 2) * XT_PITCH + m] = f2;
        xT[pp][(d + 3) * XT_PITCH + m] = f3;
        xS[pp][m * 64 + (cc + 0) * 4 + tq] = f0;
        xS[pp][m * 64 + (cc + 1) * 4 + tq] = f1;
        xS[pp][m * 64 + (cc + 2) * 4 + tq] = f2;
        xS[pp][m * 64 + (cc + 3) * 4 + tq] = f3;
    }
    __syncthreads();

    // K-invariant x parts of B fragments: xv8[t][j] = x[quad*8+j][16t+col]
    v8h xv8[4];
    #pragma unroll
    for (int t = 0; t < 4; ++t)
        xv8[t] = *(const v8h*)(&xT[p][(16 * t + col) * XT_PITCH + quad * 8]);

    const _Float16* WbL0 = Wsw + (size_t)rh * 2048 + (size_t)lane * 8;
    const _Float16* WbL1 = WbL0 + W0_ELEMS;
    const _Float16* xSp  = &xS[p][col * 4];
    const _Float16* h1Sp = &h1S[p][col * 4];

    // ================= layer 0 (32 K-steps, 2x ping-pong) =================
    v4f acc[4][4];
    #pragma unroll
    for (int f = 0; f < 4; ++f)
        #pragma unroll
        for (int t = 0; t < 4; ++t) acc[f][t] = (v4f)0.0f;

    v8h A[4], B[4];
    v4h svA, svB;
    loadW4(A, WbL0);
    svA = *(const v4h*)(xSp);
    #pragma unroll 1
    for (int kp = 0; kp < 15; ++kp) {          // ks = 2kp, 2kp+1
        const _Float16* Wc = WbL0 + (size_t)kp * 8192;
        loadW4(B, Wc + 4096);
        svB = *(const v4h*)(xSp + (2 * kp + 1) * 64);
        compute16(A, svA, xv8, acc);           // tile 2kp
        loadW4(A, Wc + 8192);
        svA = *(const v4h*)(xSp + (2 * kp + 2) * 64);
        compute16(B, svB, xv8, acc);           // tile 2kp+1
    }
    // tail: ks=30,31; second prefetch pulls layer-1 tile 0 across the epilogue
    loadW4(B, WbL0 + (size_t)31 * 4096);
    svB = *(const v4h*)(xSp + 31 * 64);
    compute16(A, svA, xv8, acc);               // tile 30
    loadW4(A, WbL1);                           // layer-1 tile 0
    compute16(B, svB, xv8, acc);               // tile 31

    // ---- epilogue 0 ----
    // rh=0: rows 0..63 -> h1S[p] (packed v4h writes); rh=1: rows 64..127 -> out
    if (rh == 0) {
        #pragma unroll
        for (int f = 0; f < 4; ++f) {
            #pragma unroll
            for (int reg = 0; reg < 4; ++reg) {
                const int o = f * 16 + quad * 4 + reg;
                const float bias = b0[o];
                v4h pk;
                #pragma unroll
                for (int t = 0; t < 4; ++t) {
                    float v = acc[f][t][reg] + bias;
                    v = v > 0.0f ? v : 0.0f;
                    pk[t] = (_Float16)v;
                }
                *(v4h*)(&h1S[p][o * 64 + col * 4]) = pk;
            }
        }
    } else {
        #pragma unroll
        for (int f = 0; f < 4; ++f) {
            #pragma unroll
            for (int reg = 0; reg < 4; ++reg) {
                const int o = 64 + f * 16 + quad * 4 + reg;
                const float bias = b0[o];
                float s = 0.0f;
                #pragma unroll
                for (int t = 0; t < 4; ++t) {
                    float v = acc[f][t][reg] + bias;
                    s += (v > 0.0f ? v : 0.0f);
                }
                s += __shfl_xor(s, 1);
                s += __shfl_xor(s, 2);
                s += __shfl_xor(s, 4);
                s += __shfl_xor(s, 8);
                if (col == 0) out[(size_t)(b0i + p) * OUTC + (o - 64)] = s;
            }
        }
    }
    __syncthreads();   // h1S visible to all waves

    // ================= layer 1 (64 K-steps, 2x ping-pong) =================
    #pragma unroll
    for (int f = 0; f < 4; ++f)
        #pragma unroll
        for (int t = 0; t < 4; ++t) acc[f][t] = (v4f)0.0f;

    // A already holds layer-1 tile 0 (prefetched before the epilogue)
    svA = *(const v4h*)(h1Sp);
    #pragma unroll 1
    for (int kp = 0; kp < 31; ++kp) {          // ks = 2kp, 2kp+1
        const _Float16* Wc = WbL1 + (size_t)kp * 8192;
        loadW4(B, Wc + 4096);
        svB = *(const v4h*)(h1Sp + (2 * kp + 1) * 64);
        compute16(A, svA, xv8, acc);           // tile 2kp
        loadW4(A, Wc + 8192);
        svA = *(const v4h*)(h1Sp + (2 * kp + 2) * 64);
        compute16(B, svB, xv8, acc);           // tile 2kp+1
    }
    // tail: ks=62,63 (no further prefetch)
    loadW4(B, WbL1 + (size_t)63 * 4096);
    svB = *(const v4h*)(h1Sp + 63 * 64);
    compute16(A, svA, xv8, acc);               // tile 62
    compute16(B, svB, xv8, acc);               // tile 63

    // ---- epilogue 1: wave's 64 rows -> out[b, 64+o] ----
    #pragma unroll
    for (int f = 0; f < 4; ++f) {
        #pragma unroll
        for (int reg = 0; reg < 4; ++reg) {
            const int o = rh * 64 + f * 16 + quad * 4 + reg;
            const float bias = b1[o];
            float s = 0.0f;
            #pragma unroll
            for (int t = 0; t < 4; ++t) {
                float v = acc[f][t][reg] + bias;
                s += (v > 0.0f ? v : 0.0f);
            }
            s += __shfl_xor(s, 1);
            s += __shfl_xor(s, 2);
            s += __shfl_xor(s, 4);
            s += __shfl_xor(s, 8);
            if (col == 0) out[(size_t)(b0i + p) * OUTC + 64 + o] = s;
        }
    }
}

extern "C" void kernel_launch(void* const* d_in, const int* in_sizes, int n_in,
                              void* d_out, int out_size, void* d_ws, size_t ws_size,
                              hipStream_t stream) {
    const float* X  = (const float*)d_in[0];
    const float* W0 = (const float*)d_in[1];
    const float* b0 = (const float*)d_in[2];
    const float* W1 = (const float*)d_in[3];
    const float* b1 = (const float*)d_in[4];
    float* out = (float*)d_out;
    _Float16* wsw = (_Float16*)d_ws;  // needs 768 KB

    convert_w_kernel<<<(CVT_THREADS + 255) / 256, 256, 0, stream>>>(W0, W1, wsw);
    cin_kernel<<<BATCH / 2, 256, 0, stream>>>(X, b0, b1, wsw, out);
}